// Round 1
// baseline (338.398 us; speedup 1.0000x reference)
//
#include <hip/hip_runtime.h>

// ---------- problem constants ----------
#define BQ   8
#define NQ   8192      // unknown points per batch
#define MK   2048      // known points per batch
#define C1v  128
#define C2v  256
#define CIN  384
#define HH   256
#define MTOT (BQ*NQ)   // 65536

typedef __attribute__((ext_vector_type(8))) __bf16 bf16x8;
typedef __attribute__((ext_vector_type(4))) float f32x4;
typedef __attribute__((ext_vector_type(8))) unsigned short us8;
typedef __attribute__((ext_vector_type(4))) unsigned short us4;
typedef __attribute__((ext_vector_type(2))) unsigned short us2;

__device__ __forceinline__ unsigned short f2bf(float f) {
  unsigned int u = __builtin_bit_cast(unsigned int, f);
  u += 0x7fffu + ((u >> 16) & 1u);           // round-to-nearest-even
  return (unsigned short)(u >> 16);
}
__device__ __forceinline__ float bf2f(unsigned short h) {
  unsigned int u = ((unsigned int)h) << 16;
  return __builtin_bit_cast(float, u);
}

__device__ __forceinline__ void gload16(const void* g, void* l) {
  __builtin_amdgcn_global_load_lds((const __attribute__((address_space(1))) void*)g,
                                   (__attribute__((address_space(3))) void*)l, 16, 0, 0);
}

// ---------- 1. prep: convert W1/W2 to bf16, zero BN accumulators ----------
__global__ __launch_bounds__(256)
void prep_kernel(const float* __restrict__ W1, const float* __restrict__ W2,
                 unsigned short* __restrict__ w1b, unsigned short* __restrict__ w2b,
                 float* __restrict__ stats) {
  int i = blockIdx.x * 256 + threadIdx.x;
  if (i < HH*CIN) w1b[i] = f2bf(W1[i]);
  else if (i < HH*CIN + HH*HH) w2b[i - HH*CIN] = f2bf(W2[i - HH*CIN]);
  int z = i - (HH*CIN + HH*HH);
  if (z >= 0 && z < 1024) stats[z] = 0.f;
}

// ---------- 2. three_nn: top-3 neighbors + inverse-distance weights ----------
__global__ __launch_bounds__(256)
void nn_kernel(const float* __restrict__ unknown, const float* __restrict__ known,
               int* __restrict__ widx, float* __restrict__ wwgt) {
  __shared__ float4 kpts[MK];          // x,y,z, 0.5*|k|^2   (32 KB)
  const int b = blockIdx.y;
  const int tid = threadIdx.x;
  const float* kb = known + (size_t)b * MK * 3;
  for (int i = tid; i < MK; i += 256) {
    float x = kb[i*3+0], y = kb[i*3+1], z = kb[i*3+2];
    kpts[i] = make_float4(x, y, z, 0.5f*(x*x + y*y + z*z));
  }
  __syncthreads();

  const int q = blockIdx.x * 256 + tid;
  const float* up = unknown + ((size_t)b * NQ + q) * 3;
  const float ux = up[0], uy = up[1], uz = up[2];
  const float nu = ux*ux + uy*uy + uz*uz;

  float s0 = -3.4e38f, s1 = -3.4e38f, s2 = -3.4e38f;   // maximize s = u.k - 0.5|k|^2
  int   i0 = 0, i1 = 0, i2 = 0;
  for (int j = 0; j < MK; ++j) {
    float4 k4 = kpts[j];
    float s = fmaf(ux, k4.x, fmaf(uy, k4.y, fmaf(uz, k4.z, -k4.w)));
    if (s > s2) {
      if (s > s0)      { s2=s1;i2=i1; s1=s0;i1=i0; s0=s;i0=j; }
      else if (s > s1) { s2=s1;i2=i1; s1=s; i1=j; }
      else             { s2=s; i2=j; }
    }
  }
  float d0 = sqrtf(fmaxf(nu - 2.f*s0, 0.f)) + 1e-10f;
  float d1 = sqrtf(fmaxf(nu - 2.f*s1, 0.f)) + 1e-10f;
  float d2 = sqrtf(fmaxf(nu - 2.f*s2, 0.f)) + 1e-10f;
  float r0 = 1.f/d0, r1 = 1.f/d1, r2 = 1.f/d2;
  float rs = 1.f/(r0 + r1 + r2);
  size_t p = (size_t)b * NQ + q;
  widx[p*3+0] = i0; widx[p*3+1] = i1; widx[p*3+2] = i2;
  wwgt[p*3+0] = r0*rs; wwgt[p*3+1] = r1*rs; wwgt[p*3+2] = r2*rs;
}

// ---------- 3. interpolate + concat -> X [65536][384] bf16 ----------
__global__ __launch_bounds__(256)
void interp_kernel(const float* __restrict__ kf, const float* __restrict__ uf,
                   const int* __restrict__ widx, const float* __restrict__ wwgt,
                   unsigned short* __restrict__ X) {
  const int p = blockIdx.x * 4 + (threadIdx.x >> 6);
  const int lane = threadIdx.x & 63;
  const int b = p >> 13, q = p & 8191;
  const int*   ip = widx + (size_t)p * 3;
  const float* wp = wwgt + (size_t)p * 3;
  int   j0 = ip[0], j1 = ip[1], j2 = ip[2];
  float w0 = wp[0], w1 = wp[1], w2 = wp[2];
  const float4* f0 = (const float4*)(kf + ((size_t)b*MK + j0) * C2v);
  const float4* f1 = (const float4*)(kf + ((size_t)b*MK + j1) * C2v);
  const float4* f2 = (const float4*)(kf + ((size_t)b*MK + j2) * C2v);
  float4 a = f0[lane], c = f1[lane], d = f2[lane];
  unsigned short* xr = X + (size_t)p * CIN;
  us4 v;
  v[0] = f2bf(w0*a.x + w1*c.x + w2*d.x);
  v[1] = f2bf(w0*a.y + w1*c.y + w2*d.y);
  v[2] = f2bf(w0*a.z + w1*c.z + w2*d.z);
  v[3] = f2bf(w0*a.w + w1*c.w + w2*d.w);
  *(us4*)(xr + lane*4) = v;
  float2 uu = *(const float2*)(uf + ((size_t)b*NQ + q) * C1v + lane*2);
  us2 w; w[0] = f2bf(uu.x); w[1] = f2bf(uu.y);
  *(us2*)(xr + C2v + lane*2) = w;
}

// ---------- 4. GEMM: Y[M][256] = A[M][K] * Bw[256][K]^T + bias, + BN stats ----------
template<int K, bool OUT_BF16>
__global__ __launch_bounds__(256)
void gemm_kernel(const unsigned short* __restrict__ A,
                 const unsigned short* __restrict__ Bw,
                 const float* __restrict__ bias,
                 void* __restrict__ Out,
                 float* __restrict__ gsum, float* __restrict__ gsq) {
  __shared__ unsigned short As[128][64];   // 16 KB
  __shared__ unsigned short Bs[128][64];   // 16 KB
  const int tid  = threadIdx.x;
  const int lane = tid & 63;
  const int wave = tid >> 6;          // 0..3
  const int bm = blockIdx.x, bn = blockIdx.y;
  const int wm = wave >> 1, wn = wave & 1;

  f32x4 acc[4][4];
  const f32x4 zero = {0.f, 0.f, 0.f, 0.f};
  #pragma unroll
  for (int m = 0; m < 4; ++m)
    #pragma unroll
    for (int n = 0; n < 4; ++n) acc[m][n] = zero;

  for (int k0 = 0; k0 < K; k0 += 64) {
    #pragma unroll
    for (int i = 0; i < 4; ++i) {
      const int cbase = wave*64 + i*256;          // wave-uniform chunk base
      const int c = cbase + lane;                 // per-lane chunk (16 B)
      const int row = c >> 3, col = (c & 7) * 8;
      gload16(A  + ((size_t)(bm*128 + row))*K + k0 + col, (unsigned short*)As + cbase*8);
      gload16(Bw + ((size_t)(bn*128 + row))*K + k0 + col, (unsigned short*)Bs + cbase*8);
    }
    __syncthreads();
    const int kq = (lane >> 4) * 8;
    #pragma unroll
    for (int kk = 0; kk < 64; kk += 32) {
      bf16x8 af[4], bfr[4];
      #pragma unroll
      for (int m = 0; m < 4; ++m)
        af[m] = *(const bf16x8*)&As[wm*64 + m*16 + (lane & 15)][kk + kq];
      #pragma unroll
      for (int n = 0; n < 4; ++n)
        bfr[n] = *(const bf16x8*)&Bs[wn*64 + n*16 + (lane & 15)][kk + kq];
      #pragma unroll
      for (int m = 0; m < 4; ++m)
        #pragma unroll
        for (int n = 0; n < 4; ++n)
          acc[m][n] = __builtin_amdgcn_mfma_f32_16x16x32_bf16(af[m], bfr[n], acc[m][n], 0, 0, 0);
    }
    __syncthreads();
  }

  // epilogue: bias, store, per-channel sum/sumsq
  float* s_sum = (float*)&As[0][0];   // [2][128]
  float* s_sq  = s_sum + 256;         // [2][128]
  #pragma unroll
  for (int n = 0; n < 4; ++n) {
    const int cb   = wn*64 + n*16 + (lane & 15);
    const int gcol = bn*128 + cb;
    const float bv = bias[gcol];
    float sum = 0.f, sq = 0.f;
    #pragma unroll
    for (int m = 0; m < 4; ++m) {
      const size_t grow = (size_t)bm*128 + wm*64 + m*16 + (lane >> 4)*4;
      #pragma unroll
      for (int qq = 0; qq < 4; ++qq) {
        float y = acc[m][n][qq] + bv;
        sum += y; sq += y*y;
        if (OUT_BF16) ((unsigned short*)Out)[(grow+qq)*256 + gcol] = f2bf(y);
        else          ((float*)Out)[(grow+qq)*256 + gcol] = y;
      }
    }
    sum += __shfl_xor(sum, 16, 64); sum += __shfl_xor(sum, 32, 64);
    sq  += __shfl_xor(sq , 16, 64); sq  += __shfl_xor(sq , 32, 64);
    if (lane < 16) { s_sum[wm*128 + cb] = sum; s_sq[wm*128 + cb] = sq; }
  }
  __syncthreads();
  if (tid < 128) {
    atomicAdd(&gsum[bn*128 + tid], s_sum[tid] + s_sum[128 + tid]);
    atomicAdd(&gsq [bn*128 + tid], s_sq [tid] + s_sq [128 + tid]);
  }
}

// ---------- 5. BN stats finalize: scale/shift ----------
__global__ __launch_bounds__(256)
void stats_fin(const float* __restrict__ gsum, const float* __restrict__ gsq,
               const float* __restrict__ g, const float* __restrict__ beta,
               float* __restrict__ scale, float* __restrict__ shift) {
  int c = threadIdx.x;
  float mu  = gsum[c] * (1.f/65536.f);
  float var = gsq[c]  * (1.f/65536.f) - mu*mu;
  float sc  = g[c] * rsqrtf(var + 1e-5f);
  scale[c] = sc;
  shift[c] = beta[c] - mu*sc;
}

// ---------- 6. BN+ReLU elementwise (bf16 -> bf16) ----------
__global__ __launch_bounds__(256)
void bnrelu_kernel(const unsigned short* __restrict__ Y,
                   const float* __restrict__ scale, const float* __restrict__ shift,
                   unsigned short* __restrict__ Z) {
  __shared__ float sc[256], sh[256];
  if (threadIdx.x < 256) { sc[threadIdx.x] = scale[threadIdx.x]; sh[threadIdx.x] = shift[threadIdx.x]; }
  __syncthreads();
  size_t i = ((size_t)blockIdx.x * 256 + threadIdx.x) * 8;
  int c0 = (int)(i & 255);
  us8 v = *(const us8*)(Y + i);
  us8 o;
  #pragma unroll
  for (int j = 0; j < 8; ++j) {
    float y = bf2f(v[j]) * sc[c0+j] + sh[c0+j];
    o[j] = f2bf(fmaxf(y, 0.f));
  }
  *(us8*)(Z + i) = o;
}

// ---------- 7. final BN+ReLU in-place on d_out (fp32) ----------
__global__ __launch_bounds__(256)
void final_kernel(float* __restrict__ Y,
                  const float* __restrict__ scale, const float* __restrict__ shift) {
  __shared__ float sc[256], sh[256];
  if (threadIdx.x < 256) { sc[threadIdx.x] = scale[threadIdx.x]; sh[threadIdx.x] = shift[threadIdx.x]; }
  __syncthreads();
  size_t i = ((size_t)blockIdx.x * 256 + threadIdx.x) * 4;
  int c0 = (int)(i & 255);
  float4 v = *(float4*)(Y + i);
  v.x = fmaxf(fmaf(v.x, sc[c0+0], sh[c0+0]), 0.f);
  v.y = fmaxf(fmaf(v.y, sc[c0+1], sh[c0+1]), 0.f);
  v.z = fmaxf(fmaf(v.z, sc[c0+2], sh[c0+2]), 0.f);
  v.w = fmaxf(fmaf(v.w, sc[c0+3], sh[c0+3]), 0.f);
  *(float4*)(Y + i) = v;
}

// ---------- launch ----------
extern "C" void kernel_launch(void* const* d_in, const int* in_sizes, int n_in,
                              void* d_out, int out_size, void* d_ws, size_t ws_size,
                              hipStream_t stream) {
  const float* unknown = (const float*)d_in[0];
  const float* known   = (const float*)d_in[1];
  const float* uf      = (const float*)d_in[2];
  const float* kf      = (const float*)d_in[3];
  const float* W1      = (const float*)d_in[4];
  const float* b1      = (const float*)d_in[5];
  const float* g1      = (const float*)d_in[6];
  const float* be1     = (const float*)d_in[7];
  const float* W2      = (const float*)d_in[8];
  const float* b2      = (const float*)d_in[9];
  const float* g2      = (const float*)d_in[10];
  const float* be2     = (const float*)d_in[11];

  char* ws = (char*)d_ws;
  unsigned short* X    = (unsigned short*)(ws);                 // 65536*384*2 = 50,331,648
  unsigned short* Y1   = (unsigned short*)(ws + 50331648);      // 65536*256*2 = 33,554,432
  unsigned short* w1b  = (unsigned short*)(ws + 83886080);      // 196,608
  unsigned short* w2b  = (unsigned short*)(ws + 84082688);      // 131,072
  int*            widx = (int*)  (ws + 84213760);               // 786,432
  float*          wwgt = (float*)(ws + 85000192);               // 786,432
  float*          stats= (float*)(ws + 85786624);               // 8 KB
  float *sum1 = stats,        *sq1 = stats + 256;
  float *sum2 = stats + 512,  *sq2 = stats + 768;
  float *scale1 = stats + 1024, *shift1 = stats + 1280;
  float *scale2 = stats + 1536, *shift2 = stats + 1792;
  float* out = (float*)d_out;

  prep_kernel<<<644, 256, 0, stream>>>(W1, W2, w1b, w2b, stats);
  nn_kernel<<<dim3(32, 8), 256, 0, stream>>>(unknown, known, widx, wwgt);
  interp_kernel<<<16384, 256, 0, stream>>>(kf, uf, widx, wwgt, X);
  gemm_kernel<CIN, true ><<<dim3(512, 2), 256, 0, stream>>>(X, w1b, b1, Y1, sum1, sq1);
  stats_fin<<<1, 256, 0, stream>>>(sum1, sq1, g1, be1, scale1, shift1);
  bnrelu_kernel<<<8192, 256, 0, stream>>>(Y1, scale1, shift1, X);   // X reused as layer-2 input
  gemm_kernel<HH, false><<<dim3(512, 2), 256, 0, stream>>>(X, w2b, b2, out, sum2, sq2);
  stats_fin<<<1, 256, 0, stream>>>(sum2, sq2, g2, be2, scale2, shift2);
  final_kernel<<<16384, 256, 0, stream>>>(out, scale2, shift2);
}

// Round 2
// 212.526 us; speedup vs baseline: 1.5923x; 1.5923x over previous
//
#include <hip/hip_runtime.h>

// ---------- problem constants ----------
#define BQ   8
#define NQ   8192      // unknown points per batch
#define MK   2048      // known points per batch
#define C1v  128
#define C2v  256
#define CIN  384
#define HH   256
#define MTOT (BQ*NQ)   // 65536

typedef __attribute__((ext_vector_type(8))) __bf16 bf16x8;
typedef __attribute__((ext_vector_type(4))) float f32x4;
typedef __attribute__((ext_vector_type(8))) unsigned short us8;
typedef __attribute__((ext_vector_type(4))) unsigned short us4;
typedef __attribute__((ext_vector_type(2))) unsigned short us2;

__device__ __forceinline__ unsigned short f2bf(float f) {
  unsigned int u = __builtin_bit_cast(unsigned int, f);
  u += 0x7fffu + ((u >> 16) & 1u);           // round-to-nearest-even
  return (unsigned short)(u >> 16);
}
__device__ __forceinline__ float bf2f(unsigned short h) {
  unsigned int u = ((unsigned int)h) << 16;
  return __builtin_bit_cast(float, u);
}

__device__ __forceinline__ void gload16(const void* g, void* l) {
  __builtin_amdgcn_global_load_lds((const __attribute__((address_space(1))) void*)g,
                                   (__attribute__((address_space(3))) void*)l, 16, 0, 0);
}

// ---------- 1. prep: convert W1/W2 to bf16, zero BN accumulators ----------
__global__ __launch_bounds__(256)
void prep_kernel(const float* __restrict__ W1, const float* __restrict__ W2,
                 unsigned short* __restrict__ w1b, unsigned short* __restrict__ w2b,
                 float* __restrict__ stats) {
  int i = blockIdx.x * 256 + threadIdx.x;
  if (i < HH*CIN) w1b[i] = f2bf(W1[i]);
  else if (i < HH*CIN + HH*HH) w2b[i - HH*CIN] = f2bf(W2[i - HH*CIN]);
  int z = i - (HH*CIN + HH*HH);
  if (z >= 0 && z < 1024) stats[z] = 0.f;
}

// ---------- 2. three_nn: 64 queries/block, 4-way chunk split, branchless top-3 ----------
__global__ __launch_bounds__(256)
void nn_kernel(const float* __restrict__ unknown, const float* __restrict__ known,
               int* __restrict__ widx, float* __restrict__ wwgt) {
  __shared__ float4 kpts[MK];          // x,y,z, 0.5*|k|^2   (32 KB)
  __shared__ float  ps[4][64][3];      // partial scores [chunk][query][rank]
  __shared__ int    pi[4][64][3];      // partial indices
  const int b = blockIdx.y;
  const int tid = threadIdx.x;
  const int wave = tid >> 6, lane = tid & 63;
  const float* kb = known + (size_t)b * MK * 3;
  for (int i = tid; i < MK; i += 256) {
    float x = kb[i*3+0], y = kb[i*3+1], z = kb[i*3+2];
    kpts[i] = make_float4(x, y, z, 0.5f*(x*x + y*y + z*z));
  }
  __syncthreads();

  const int q = blockIdx.x * 64 + lane;
  const float* up = unknown + ((size_t)b * NQ + q) * 3;
  const float ux = up[0], uy = up[1], uz = up[2];
  const float nu = ux*ux + uy*uy + uz*uz;

  // maximize s = u.k - 0.5|k|^2  (monotone in -d^2); each wave scans its chunk
  float s0 = -3.4e38f, s1 = -3.4e38f, s2 = -3.4e38f;
  int   i0 = 0, i1 = 0, i2 = 0;
  const int jbase = wave * 512;
  #pragma unroll 4
  for (int j = 0; j < 512; ++j) {
    float4 k4 = kpts[jbase + j];
    float s = fmaf(ux, k4.x, fmaf(uy, k4.y, fmaf(uz, k4.z, -k4.w)));
    const int jj = jbase + j;
    const bool g0 = s > s0, g1 = s > s1, g2 = s > s2;
    s2 = g1 ? s1 : (g2 ? s : s2);   i2 = g1 ? i1 : (g2 ? jj : i2);
    s1 = g0 ? s0 : (g1 ? s : s1);   i1 = g0 ? i0 : (g1 ? jj : i1);
    s0 = g0 ? s  : s0;              i0 = g0 ? jj : i0;
  }
  ps[wave][lane][0] = s0; ps[wave][lane][1] = s1; ps[wave][lane][2] = s2;
  pi[wave][lane][0] = i0; pi[wave][lane][1] = i1; pi[wave][lane][2] = i2;
  __syncthreads();

  if (tid < 64) {   // wave 0, lane == tid owns the same query q (has ux..nu live)
    float m0 = -3.4e38f, m1 = -3.4e38f, m2 = -3.4e38f;
    int   a0 = 0, a1 = 0, a2 = 0;
    #pragma unroll
    for (int c = 0; c < 4; ++c)
      #pragma unroll
      for (int r = 0; r < 3; ++r) {
        float s = ps[c][tid][r]; int jj = pi[c][tid][r];
        const bool g0 = s > m0, g1 = s > m1, g2 = s > m2;
        m2 = g1 ? m1 : (g2 ? s : m2);   a2 = g1 ? a1 : (g2 ? jj : a2);
        m1 = g0 ? m0 : (g1 ? s : m1);   a1 = g0 ? a0 : (g1 ? jj : a1);
        m0 = g0 ? s  : m0;              a0 = g0 ? jj : a0;
      }
    float d0 = sqrtf(fmaxf(nu - 2.f*m0, 0.f)) + 1e-10f;
    float d1 = sqrtf(fmaxf(nu - 2.f*m1, 0.f)) + 1e-10f;
    float d2 = sqrtf(fmaxf(nu - 2.f*m2, 0.f)) + 1e-10f;
    float r0 = 1.f/d0, r1 = 1.f/d1, r2 = 1.f/d2;
    float rs = 1.f/(r0 + r1 + r2);
    size_t p = (size_t)b * NQ + q;
    widx[p*3+0] = a0;    widx[p*3+1] = a1;    widx[p*3+2] = a2;
    wwgt[p*3+0] = r0*rs; wwgt[p*3+1] = r1*rs; wwgt[p*3+2] = r2*rs;
  }
}

// ---------- 3. interpolate + concat -> X [65536][384] bf16 ----------
__global__ __launch_bounds__(256)
void interp_kernel(const float* __restrict__ kf, const float* __restrict__ uf,
                   const int* __restrict__ widx, const float* __restrict__ wwgt,
                   unsigned short* __restrict__ X) {
  const int p = blockIdx.x * 4 + (threadIdx.x >> 6);
  const int lane = threadIdx.x & 63;
  const int b = p >> 13, q = p & 8191;
  const int*   ip = widx + (size_t)p * 3;
  const float* wp = wwgt + (size_t)p * 3;
  int   j0 = ip[0], j1 = ip[1], j2 = ip[2];
  float w0 = wp[0], w1 = wp[1], w2 = wp[2];
  const float4* f0 = (const float4*)(kf + ((size_t)b*MK + j0) * C2v);
  const float4* f1 = (const float4*)(kf + ((size_t)b*MK + j1) * C2v);
  const float4* f2 = (const float4*)(kf + ((size_t)b*MK + j2) * C2v);
  float4 a = f0[lane], c = f1[lane], d = f2[lane];
  unsigned short* xr = X + (size_t)p * CIN;
  us4 v;
  v[0] = f2bf(w0*a.x + w1*c.x + w2*d.x);
  v[1] = f2bf(w0*a.y + w1*c.y + w2*d.y);
  v[2] = f2bf(w0*a.z + w1*c.z + w2*d.z);
  v[3] = f2bf(w0*a.w + w1*c.w + w2*d.w);
  *(us4*)(xr + lane*4) = v;
  float2 uu = *(const float2*)(uf + ((size_t)b*NQ + q) * C1v + lane*2);
  us2 w; w[0] = f2bf(uu.x); w[1] = f2bf(uu.y);
  *(us2*)(xr + C2v + lane*2) = w;
}

// ---------- 4. GEMM: Y[M][256] = A[M][K] * Bw[256][K]^T + bias, + BN stats ----------
template<int K, bool OUT_BF16>
__global__ __launch_bounds__(256)
void gemm_kernel(const unsigned short* __restrict__ A,
                 const unsigned short* __restrict__ Bw,
                 const float* __restrict__ bias,
                 void* __restrict__ Out,
                 float* __restrict__ gsum, float* __restrict__ gsq) {
  __shared__ unsigned short As[128][64];   // 16 KB
  __shared__ unsigned short Bs[128][64];   // 16 KB
  const int tid  = threadIdx.x;
  const int lane = tid & 63;
  const int wave = tid >> 6;          // 0..3
  const int bm = blockIdx.x, bn = blockIdx.y;
  const int wm = wave >> 1, wn = wave & 1;

  f32x4 acc[4][4];
  const f32x4 zero = {0.f, 0.f, 0.f, 0.f};
  #pragma unroll
  for (int m = 0; m < 4; ++m)
    #pragma unroll
    for (int n = 0; n < 4; ++n) acc[m][n] = zero;

  for (int k0 = 0; k0 < K; k0 += 64) {
    #pragma unroll
    for (int i = 0; i < 4; ++i) {
      const int cbase = wave*64 + i*256;          // wave-uniform chunk base
      const int c = cbase + lane;                 // per-lane chunk (16 B)
      const int row = c >> 3, col = (c & 7) * 8;
      gload16(A  + ((size_t)(bm*128 + row))*K + k0 + col, (unsigned short*)As + cbase*8);
      gload16(Bw + ((size_t)(bn*128 + row))*K + k0 + col, (unsigned short*)Bs + cbase*8);
    }
    __syncthreads();
    const int kq = (lane >> 4) * 8;
    #pragma unroll
    for (int kk = 0; kk < 64; kk += 32) {
      bf16x8 af[4], bfr[4];
      #pragma unroll
      for (int m = 0; m < 4; ++m)
        af[m] = *(const bf16x8*)&As[wm*64 + m*16 + (lane & 15)][kk + kq];
      #pragma unroll
      for (int n = 0; n < 4; ++n)
        bfr[n] = *(const bf16x8*)&Bs[wn*64 + n*16 + (lane & 15)][kk + kq];
      #pragma unroll
      for (int m = 0; m < 4; ++m)
        #pragma unroll
        for (int n = 0; n < 4; ++n)
          acc[m][n] = __builtin_amdgcn_mfma_f32_16x16x32_bf16(af[m], bfr[n], acc[m][n], 0, 0, 0);
    }
    __syncthreads();
  }

  // epilogue: bias, store, per-channel sum/sumsq
  float* s_sum = (float*)&As[0][0];   // [2][128]
  float* s_sq  = s_sum + 256;         // [2][128]
  #pragma unroll
  for (int n = 0; n < 4; ++n) {
    const int cb   = wn*64 + n*16 + (lane & 15);
    const int gcol = bn*128 + cb;
    const float bv = bias[gcol];
    float sum = 0.f, sq = 0.f;
    #pragma unroll
    for (int m = 0; m < 4; ++m) {
      const size_t grow = (size_t)bm*128 + wm*64 + m*16 + (lane >> 4)*4;
      #pragma unroll
      for (int qq = 0; qq < 4; ++qq) {
        float y = acc[m][n][qq] + bv;
        sum += y; sq += y*y;
        if (OUT_BF16) ((unsigned short*)Out)[(grow+qq)*256 + gcol] = f2bf(y);
        else          ((float*)Out)[(grow+qq)*256 + gcol] = y;
      }
    }
    sum += __shfl_xor(sum, 16, 64); sum += __shfl_xor(sum, 32, 64);
    sq  += __shfl_xor(sq , 16, 64); sq  += __shfl_xor(sq , 32, 64);
    if (lane < 16) { s_sum[wm*128 + cb] = sum; s_sq[wm*128 + cb] = sq; }
  }
  __syncthreads();
  if (tid < 128) {
    atomicAdd(&gsum[bn*128 + tid], s_sum[tid] + s_sum[128 + tid]);
    atomicAdd(&gsq [bn*128 + tid], s_sq [tid] + s_sq [128 + tid]);
  }
}

// ---------- 5. BN stats finalize: scale/shift ----------
__global__ __launch_bounds__(256)
void stats_fin(const float* __restrict__ gsum, const float* __restrict__ gsq,
               const float* __restrict__ g, const float* __restrict__ beta,
               float* __restrict__ scale, float* __restrict__ shift) {
  int c = threadIdx.x;
  float mu  = gsum[c] * (1.f/65536.f);
  float var = gsq[c]  * (1.f/65536.f) - mu*mu;
  float sc  = g[c] * rsqrtf(var + 1e-5f);
  scale[c] = sc;
  shift[c] = beta[c] - mu*sc;
}

// ---------- 6. BN+ReLU elementwise (bf16 -> bf16) ----------
__global__ __launch_bounds__(256)
void bnrelu_kernel(const unsigned short* __restrict__ Y,
                   const float* __restrict__ scale, const float* __restrict__ shift,
                   unsigned short* __restrict__ Z) {
  __shared__ float sc[256], sh[256];
  if (threadIdx.x < 256) { sc[threadIdx.x] = scale[threadIdx.x]; sh[threadIdx.x] = shift[threadIdx.x]; }
  __syncthreads();
  size_t i = ((size_t)blockIdx.x * 256 + threadIdx.x) * 8;
  int c0 = (int)(i & 255);
  us8 v = *(const us8*)(Y + i);
  us8 o;
  #pragma unroll
  for (int j = 0; j < 8; ++j) {
    float y = bf2f(v[j]) * sc[c0+j] + sh[c0+j];
    o[j] = f2bf(fmaxf(y, 0.f));
  }
  *(us8*)(Z + i) = o;
}

// ---------- 7. final BN+ReLU in-place on d_out (fp32) ----------
__global__ __launch_bounds__(256)
void final_kernel(float* __restrict__ Y,
                  const float* __restrict__ scale, const float* __restrict__ shift) {
  __shared__ float sc[256], sh[256];
  if (threadIdx.x < 256) { sc[threadIdx.x] = scale[threadIdx.x]; sh[threadIdx.x] = shift[threadIdx.x]; }
  __syncthreads();
  size_t i = ((size_t)blockIdx.x * 256 + threadIdx.x) * 4;
  int c0 = (int)(i & 255);
  float4 v = *(float4*)(Y + i);
  v.x = fmaxf(fmaf(v.x, sc[c0+0], sh[c0+0]), 0.f);
  v.y = fmaxf(fmaf(v.y, sc[c0+1], sh[c0+1]), 0.f);
  v.z = fmaxf(fmaf(v.z, sc[c0+2], sh[c0+2]), 0.f);
  v.w = fmaxf(fmaf(v.w, sc[c0+3], sh[c0+3]), 0.f);
  *(float4*)(Y + i) = v;
}

// ---------- launch ----------
extern "C" void kernel_launch(void* const* d_in, const int* in_sizes, int n_in,
                              void* d_out, int out_size, void* d_ws, size_t ws_size,
                              hipStream_t stream) {
  const float* unknown = (const float*)d_in[0];
  const float* known   = (const float*)d_in[1];
  const float* uf      = (const float*)d_in[2];
  const float* kf      = (const float*)d_in[3];
  const float* W1      = (const float*)d_in[4];
  const float* b1      = (const float*)d_in[5];
  const float* g1      = (const float*)d_in[6];
  const float* be1     = (const float*)d_in[7];
  const float* W2      = (const float*)d_in[8];
  const float* b2      = (const float*)d_in[9];
  const float* g2      = (const float*)d_in[10];
  const float* be2     = (const float*)d_in[11];

  char* ws = (char*)d_ws;
  unsigned short* X    = (unsigned short*)(ws);                 // 65536*384*2 = 50,331,648
  unsigned short* Y1   = (unsigned short*)(ws + 50331648);      // 65536*256*2 = 33,554,432
  unsigned short* w1b  = (unsigned short*)(ws + 83886080);      // 196,608
  unsigned short* w2b  = (unsigned short*)(ws + 84082688);      // 131,072
  int*            widx = (int*)  (ws + 84213760);               // 786,432
  float*          wwgt = (float*)(ws + 85000192);               // 786,432
  float*          stats= (float*)(ws + 85786624);               // 8 KB
  float *sum1 = stats,        *sq1 = stats + 256;
  float *sum2 = stats + 512,  *sq2 = stats + 768;
  float *scale1 = stats + 1024, *shift1 = stats + 1280;
  float *scale2 = stats + 1536, *shift2 = stats + 1792;
  float* out = (float*)d_out;

  prep_kernel<<<644, 256, 0, stream>>>(W1, W2, w1b, w2b, stats);
  nn_kernel<<<dim3(128, 8), 256, 0, stream>>>(unknown, known, widx, wwgt);
  interp_kernel<<<16384, 256, 0, stream>>>(kf, uf, widx, wwgt, X);
  gemm_kernel<CIN, true ><<<dim3(512, 2), 256, 0, stream>>>(X, w1b, b1, Y1, sum1, sq1);
  stats_fin<<<1, 256, 0, stream>>>(sum1, sq1, g1, be1, scale1, shift1);
  bnrelu_kernel<<<8192, 256, 0, stream>>>(Y1, scale1, shift1, X);   // X reused as layer-2 input
  gemm_kernel<HH, false><<<dim3(512, 2), 256, 0, stream>>>(X, w2b, b2, out, sum2, sq2);
  stats_fin<<<1, 256, 0, stream>>>(sum2, sq2, g2, be2, scale2, shift2);
  final_kernel<<<16384, 256, 0, stream>>>(out, scale2, shift2);
}